// Round 4
// baseline (1113.702 us; speedup 1.0000x reference)
//
#include <hip/hip_runtime.h>

// ---------------------------------------------------------------------------
// CasualGraph on MI355X. 3 layers of source = T^T (T x); x = LN(source+x0);
// then per-hyperedge mean of final pre-norm source, global max over edges.
// bf16 MFMA 16x16x32, fp32 accumulate.
//
// GEMM: BM=256(=M), BN=256, BK=64, split-K=8, 512 threads (8 waves, 2x4).
// Depth-2 LDS pipeline with RAW s_waitcnt vmcnt(8)/s_barrier (never a full
// vmcnt(0) drain in steady state) -- keeps ~64 KB/CU of global_load_lds DMA
// in flight across iterations instead of draining each __syncthreads.
// ---------------------------------------------------------------------------

typedef __bf16 bf16;
typedef __bf16 bf16x8 __attribute__((ext_vector_type(8)));
typedef float f32x4 __attribute__((ext_vector_type(4)));

__device__ __forceinline__ void gld_lds16(const bf16* g, bf16* l) {
  __builtin_amdgcn_global_load_lds(
      (const __attribute__((address_space(1))) unsigned int*)g,
      (__attribute__((address_space(3))) unsigned int*)l, 16, 0, 0);
}

// ---------------------------------------------------------------------------
// P[z][m][n] = sum_{k in split z} A[m][k]*B[n][k].  A,B bf16 K-contiguous.
// LDS row = 128 B = 8 x 16-B chunks; LDS[row][c] holds global chunk c^(row&7)
// (swizzle folded into the GLOBAL index; global_load_lds scatters lane i ->
//  base + 16*i). ds_read b128 fragments then alias <=2-way (free).
// ---------------------------------------------------------------------------
template <int BN>
__global__ __launch_bounds__(512) void gemm_bt(const bf16* __restrict__ A,
                                               const bf16* __restrict__ B,
                                               float* __restrict__ P,
                                               int N, int K, int Ks) {
  constexpr int BM = 256, BK = 64;
  constexpr int TM = 8, TN = BN / 64;        // wave tile 128 x (BN/4)
  constexpr int QA = BM / 64, QB = BN / 64;  // staging insts per wave

  __shared__ __align__(16) bf16 As[2][BM * BK];  // 32 KB each
  __shared__ __align__(16) bf16 Bs[2][BN * BK];  // 32 KB each (BN=256)

  const int t = threadIdx.x, w = t >> 6, l = t & 63;
  // one wave-inst covers 8 rows x 128 B; lane l -> row l>>3, LDS chunk l&7,
  // which must receive global chunk (l&7)^(row&7)
  const int srow = l >> 3;
  const int schunk = (l & 7) ^ srow;
  const int n0 = blockIdx.x * BN;
  const int kbase = blockIdx.z * Ks;

  const bf16* gA = A + (size_t)(w * 8 + srow) * K + kbase + schunk * 8;
  const bf16* gB = B + (size_t)(n0 + w * 8 + srow) * K + kbase + schunk * 8;

  auto stage = [&](int kk, int buf) {
    const size_t ko = (size_t)kk * BK;
#pragma unroll
    for (int q = 0; q < QA; ++q)
      gld_lds16(gA + (size_t)(q * 64) * K + ko,
                &As[buf][(q * 64 + w * 8) * BK]);
#pragma unroll
    for (int q = 0; q < QB; ++q)
      gld_lds16(gB + (size_t)(q * 64) * K + ko,
                &Bs[buf][(q * 64 + w * 8) * BK]);
  };

  const int lm = l & 15, kq = l >> 4;
  const int wm = (w >> 2) * 128;       // wave row base (2 rows of waves)
  const int wn = (w & 3) * (TN * 16);  // wave col base (4 cols of waves)

  f32x4 acc[TM][TN] = {};
  const int nk = Ks / BK;

  stage(0, 0);
  stage(1, 1);

  for (int kk = 0; kk < nk; ++kk) {
    const int buf = kk & 1;
    // wait ONLY this buffer's 8 DMA insts (next tile's 8 stay in flight);
    // full drain only on the last iteration.
    if (kk + 1 < nk)
      asm volatile("s_waitcnt vmcnt(8)" ::: "memory");
    else
      asm volatile("s_waitcnt vmcnt(0)" ::: "memory");
    asm volatile("s_barrier" ::: "memory");

#pragma unroll
    for (int ks = 0; ks < 2; ++ks) {
      bf16x8 af[TM], bfr[TN];
#pragma unroll
      for (int i = 0; i < TM; ++i) {
        const int r = wm + i * 16 + lm;
        const int c = ((ks * 4 + kq) ^ (r & 7)) * 8;
        af[i] = *(const bf16x8*)(&As[buf][r * BK + c]);
      }
#pragma unroll
      for (int j = 0; j < TN; ++j) {
        const int r = wn + j * 16 + lm;
        const int c = ((ks * 4 + kq) ^ (r & 7)) * 8;
        bfr[j] = *(const bf16x8*)(&Bs[buf][r * BK + c]);
      }
#pragma unroll
      for (int i = 0; i < TM; ++i)
#pragma unroll
        for (int j = 0; j < TN; ++j)
          acc[i][j] = __builtin_amdgcn_mfma_f32_16x16x32_bf16(af[i], bfr[j],
                                                              acc[i][j], 0, 0, 0);
    }
    // all waves done reading buf before anyone DMAs tile kk+2 into its slot
    asm volatile("s_barrier" ::: "memory");
    if (kk + 2 < nk) stage(kk + 2, buf);
  }

  // epilogue: C/D layout col = lane&15, row = kq*4 + r
  float* Pz = P + (size_t)blockIdx.z * BM * N;
#pragma unroll
  for (int i = 0; i < TM; ++i) {
    const int mrow = wm + i * 16 + kq * 4;
#pragma unroll
    for (int j = 0; j < TN; ++j) {
      const int col = n0 + wn + j * 16 + lm;
#pragma unroll
      for (int r = 0; r < 4; ++r)
        Pz[(size_t)(mrow + r) * N + col] = acc[i][j][r];
    }
  }
}

// ---------------------------------------------------------------------------
// out[i] = bf16( sum_{s<S} P[s][i] ), float4-vectorized.
// ---------------------------------------------------------------------------
template <int S>
__global__ __launch_bounds__(256) void reduceS_bf16(const float* __restrict__ P,
                                                    bf16* __restrict__ out,
                                                    size_t MN) {
  const size_t i4 = ((size_t)blockIdx.x * 256 + threadIdx.x) * 4;
  if (i4 >= MN) return;
  f32x4 a = *(const f32x4*)(P + i4);
#pragma unroll
  for (int z = 1; z < S; ++z) a = a + *(const f32x4*)(P + (size_t)z * MN + i4);
  bf16 o[4] = {(bf16)a[0], (bf16)a[1], (bf16)a[2], (bf16)a[3]};
  *(int2*)(out + i4) = *(const int2*)o;
}

// ---------------------------------------------------------------------------
// 64x64 LDS tile transpose/convert: src [R][C] f32 ->
//   cpy [R][C] bf16 (opt), trb [C][R] bf16 (opt), trf [C][R] f32 (opt).
// ---------------------------------------------------------------------------
__global__ __launch_bounds__(256) void transpose_conv(
    const float* __restrict__ src, int R, int C, bf16* __restrict__ cpy,
    bf16* __restrict__ trb, float* __restrict__ trf) {
  __shared__ float tile[64][65];
  const int t = threadIdx.x;
  const int col = t & 63, rb4 = t >> 6;
  const int r0 = blockIdx.y * 64, c0 = blockIdx.x * 64;
#pragma unroll
  for (int rr = 0; rr < 64; rr += 4) {
    const int row = rr + rb4;
    const float v = src[(size_t)(r0 + row) * C + c0 + col];
    tile[row][col] = v;
    if (cpy) cpy[(size_t)(r0 + row) * C + c0 + col] = (bf16)v;
  }
  __syncthreads();
#pragma unroll
  for (int rr = 0; rr < 64; rr += 4) {
    const int row = rr + rb4;
    const float v = tile[col][row];
    const size_t di = (size_t)(c0 + row) * R + r0 + col;
    if (trb) trb[di] = (bf16)v;
    if (trf) trf[di] = v;
  }
}

// ---------------------------------------------------------------------------
// LayerNorm over d, fused 8-way split-K reduce. block (32 nodes, 8 d-groups)
// ---------------------------------------------------------------------------
__global__ __launch_bounds__(256) void ln_kernel(const float* __restrict__ P,
                                                 const float* __restrict__ x0t,
                                                 const float* __restrict__ gamma,
                                                 const float* __restrict__ beta,
                                                 bf16* __restrict__ Xt) {
  constexpr size_t MN = (size_t)256 * 8192;
  const int tx = threadIdx.x;
  const int ty = threadIdx.y;
  const int i = blockIdx.x * 32 + tx;
  float vbuf[32];
  float s = 0.f, s2 = 0.f;
#pragma unroll
  for (int dd = 0; dd < 32; ++dd) {
    const int d = ty * 32 + dd;
    const size_t idx = (size_t)d * 8192 + i;
    float v = x0t[idx];
#pragma unroll
    for (int z = 0; z < 8; ++z) v += P[(size_t)z * MN + idx];
    vbuf[dd] = v;
    s += v;
    s2 += v * v;
  }
  __shared__ float S[8][32], Q[8][32];
  S[ty][tx] = s;
  Q[ty][tx] = s2;
  __syncthreads();
  __shared__ float MU[32], RS[32];
  if (ty == 0) {
    float a = 0.f, b = 0.f;
#pragma unroll
    for (int r = 0; r < 8; ++r) {
      a += S[r][tx];
      b += Q[r][tx];
    }
    const float mu = a * (1.0f / 256.0f);
    const float var = b * (1.0f / 256.0f) - mu * mu;
    MU[tx] = mu;
    RS[tx] = rsqrtf(var + 1e-5f);
  }
  __syncthreads();
  const float mu = MU[tx], rs = RS[tx];
#pragma unroll
  for (int dd = 0; dd < 32; ++dd) {
    const int d = ty * 32 + dd;
    const float y = (vbuf[dd] - mu) * rs * gamma[d] + beta[d];
    Xt[(size_t)d * 8192 + i] = (bf16)y;
  }
}

// ---------------------------------------------------------------------------
// inv_counts[e] = 1 / sum_i H[i][e]   (from Htb rows, coalesced)
// ---------------------------------------------------------------------------
__global__ __launch_bounds__(256) void counts_kernel(const bf16* __restrict__ Htb,
                                                     float* __restrict__ invc) {
  const int e = blockIdx.x;
  const bf16* row = Htb + (size_t)e * 8192;
  float s = 0.f;
  for (int i = threadIdx.x; i < 8192; i += 256) s += (float)row[i];
  __shared__ float red[256];
  red[threadIdx.x] = s;
  __syncthreads();
  for (int k = 128; k > 0; k >>= 1) {
    if (threadIdx.x < k) red[threadIdx.x] += red[threadIdx.x + k];
    __syncthreads();
  }
  if (threadIdx.x == 0) invc[e] = 1.0f / red[0];
}

// ---------------------------------------------------------------------------
// out[d] = max_e (sum_{s<S} P[s][d][e]) * invc[e]
// ---------------------------------------------------------------------------
__global__ __launch_bounds__(256) void final_max(const float* __restrict__ P,
                                                 const float* __restrict__ invc,
                                                 float* __restrict__ out,
                                                 int S) {
  constexpr size_t MN = (size_t)256 * 4096;
  const int d = blockIdx.x;
  float m = -3.4e38f;
  for (int e = threadIdx.x; e < 4096; e += 256) {
    const size_t idx = (size_t)d * 4096 + e;
    float s = 0.f;
    for (int z = 0; z < S; ++z) s += P[z * MN + idx];
    m = fmaxf(m, s * invc[e]);
  }
  __shared__ float red[256];
  red[threadIdx.x] = m;
  __syncthreads();
  for (int k = 128; k > 0; k >>= 1) {
    if (threadIdx.x < k)
      red[threadIdx.x] = fmaxf(red[threadIdx.x], red[threadIdx.x + k]);
    __syncthreads();
  }
  if (threadIdx.x == 0) out[d] = red[0];
}

// ---------------------------------------------------------------------------
extern "C" void kernel_launch(void* const* d_in, const int* in_sizes, int n_in,
                              void* d_out, int out_size, void* d_ws,
                              size_t ws_size, hipStream_t stream) {
  const float* x0 = (const float*)d_in[0];    // [8192][256]
  const float* T = (const float*)d_in[1];     // [8192][8192]
  const float* H = (const float*)d_in[2];     // [8192][4096]
  const float* gamma = (const float*)d_in[3]; // [256]
  const float* beta = (const float*)d_in[4];  // [256]

  constexpr int Nn = 8192, E = 4096, D = 256, K = 8192;

  char* w = (char*)d_ws;
  size_t off = 0;
  auto carve = [&](size_t bytes) {
    char* p = w + off;
    off += (bytes + 255) & ~(size_t)255;
    return p;
  };
  bf16* Tb = (bf16*)carve((size_t)Nn * Nn * 2);
  bf16* Tt = (bf16*)carve((size_t)Nn * Nn * 2);
  bf16* Htb = (bf16*)carve((size_t)E * Nn * 2);
  float* x0t = (float*)carve((size_t)D * Nn * 4);
  bf16* Xt = (bf16*)carve((size_t)D * Nn * 2);
  bf16* tt = (bf16*)carve((size_t)D * Nn * 2);
  bf16* stb = (bf16*)carve((size_t)D * Nn * 2);
  float* invc = (float*)carve((size_t)E * 4);
  float* P = (float*)carve((size_t)8 * D * Nn * 4);  // 64 MB partials

  if (off > ws_size) {  // workspace too small: fail loudly (out = 0)
    hipMemsetAsync(d_out, 0, (size_t)out_size * 4, stream);
    return;
  }

  // one-time layout prep
  transpose_conv<<<dim3(128, 128), 256, 0, stream>>>(T, Nn, Nn, Tb, Tt, nullptr);
  transpose_conv<<<dim3(64, 128), 256, 0, stream>>>(H, Nn, E, nullptr, Htb, nullptr);
  transpose_conv<<<dim3(4, 128), 256, 0, stream>>>(x0, Nn, D, nullptr, Xt, x0t);
  counts_kernel<<<E, 256, 0, stream>>>(Htb, invc);

  const size_t MN = (size_t)D * Nn;
  for (int layer = 0; layer < 3; ++layer) {
    // P = split-K(8) partials of  tt[d][j] = sum_k Xt[d][k] * Tb[j][k]
    gemm_bt<256><<<dim3(32, 1, 8), 512, 0, stream>>>(Xt, Tb, P, Nn, K, K / 8);
    reduceS_bf16<8><<<(int)(MN / 1024), 256, 0, stream>>>(P, tt, MN);
    // P = split-K(8) partials of  st[d][i] = sum_j tt[d][j] * Tt[i][j]
    gemm_bt<256><<<dim3(32, 1, 8), 512, 0, stream>>>(tt, Tt, P, Nn, K, K / 8);
    if (layer < 2) {
      ln_kernel<<<dim3(256), dim3(32, 8), 0, stream>>>(P, x0t, gamma, beta, Xt);
    } else {
      reduceS_bf16<8><<<(int)(MN / 1024), 256, 0, stream>>>(P, stb, MN);
    }
  }

  // P = split-K(16) partials of  sumsT[d][e] = sum_i stb[d][i] * Htb[e][i]
  gemm_bt<256><<<dim3(16, 1, 16), 512, 0, stream>>>(stb, Htb, P, E, K, K / 16);
  final_max<<<D, 256, 0, stream>>>(P, invc, (float*)d_out, 16);
}